// Round 7
// baseline (1916.309 us; speedup 1.0000x reference)
//
#include <hip/hip_runtime.h>

#define NB 4
#define NN 16384
#define NPT 1024
#define NS 32
#define CIN 64
#define C0 67
#define NSUB 8   // FPS blocks per batch

// DPP wave64 reduce ladders (VALU-only; HW-verified correct in rounds 3/5/6 passing runs)
#define DPP_MAXF(r, ctrl)                                                                   \
  {                                                                                         \
    unsigned _m = (unsigned)__builtin_amdgcn_update_dpp(                                    \
        (int)__float_as_uint(r), (int)__float_as_uint(r), ctrl, 0xf, 0xf, false);           \
    r = fmaxf(r, __uint_as_float(_m));                                                      \
  }
#define DPP_MINU(r, ctrl)                                                                   \
  {                                                                                         \
    unsigned _m = (unsigned)__builtin_amdgcn_update_dpp((int)(r), (int)(r), ctrl, 0xf, 0xf, \
                                                        false);                             \
    r = (r < _m) ? r : _m;                                                                  \
  }

// ---------------- FPS: 8 blocks per batch, 512 threads, 4 pts/thread ----------------
// Rounds 0-6: the 1-block/batch structure is pinned at ~1546us: 4/256 CUs, ~77% VALU duty,
// slot-minimal arithmetic (bit-exactness forbids FMA), conserved ~830cyc tail. The only
// remaining lever is MORE CUs. Each iteration: local scan of 2048 pts -> block winner ->
// publish to a tagged 64-bit slot -> all 8 blocks of the batch poll the 8 slots.
//   key = [dist_f32 | tag=it(10b) | 16383-j (14b)] : self-validating (no stale reads within
//   a run; tags unique for it=1..1023); (16383-j) orders ties to smallest global j, matching
//   numpy argmax. Cross-run staleness (graph replay): each block zeroes ITS slots at entry
//   (tag 0 never polled). Lap-safe: a block writes iteration it only after reading all of
//   it-1, whose writers had consumed it-2 -- overwrite cannot destroy unread data.
// Exchange via __hip_atomic_* AGENT scope (L1-bypass, device-coherent). Bounded spin
// (2^17) => deterministic fail instead of hang if co-residency ever breaks (32 blocks on
// 256 CUs: it won't). Per-point arithmetic byte-identical to the proven kernel; 8-way
// max-merge is order-independent over finite floats => value-exact vs single-block.
extern "C" __global__ __launch_bounds__(512)
void fps_kernel(const float* __restrict__ xyz, float* __restrict__ newxyz,
                unsigned long long* __restrict__ win) {
  const int gid = blockIdx.x;
  const int b = gid >> 3, sub = gid & (NSUB - 1);
  const int tid = threadIdx.x;          // 0..511
  const int wv = tid >> 6, lane = tid & 63;   // 8 waves
  const float* base = xyz + (size_t)b * (NN * 3);
  unsigned long long* slots = win + b * (2 * NSUB);  // [parity][NSUB]
  __shared__ unsigned long long part[8];  // wave winners (barrier-separated reuse is safe)
  __shared__ unsigned long long sh[8];    // polled slot keys
  if (tid == 0) {  // invalidate MY slots before any cross-block traffic (graph replay!)
    __hip_atomic_store(&slots[sub], 0ull, __ATOMIC_RELAXED, __HIP_MEMORY_SCOPE_AGENT);
    __hip_atomic_store(&slots[NSUB + sub], 0ull, __ATOMIC_RELAXED, __HIP_MEMORY_SCOPE_AGENT);
  }
  float px[4], py[4], pz[4], md[4];
#pragma unroll
  for (int k = 0; k < 4; ++k) {
    int j = (sub << 11) + (k << 9) + tid;   // this block owns j in [sub*2048, sub*2048+2048)
    px[k] = base[3 * j + 0];
    py[k] = base[3 * j + 1];
    pz[k] = base[3 * j + 2];
    md[k] = 1e10f;
  }
  float* onew = newxyz + (size_t)b * (NPT * 3);
  // iteration 0: centroid = point 0 (broadcast load, computed by every block)
  float cx = base[0], cy = base[1], cz = base[2];
  if (sub == 0 && tid == 0) { onew[0] = cx; onew[1] = cy; onew[2] = cz; }
  for (int it = 1; it < NPT; ++it) {
    const int p = it & 1;
    float bestv = -1.0f; int bestk = 0;
#pragma unroll
    for (int k = 0; k < 4; ++k) {
      // match numpy exactly: no FMA contraction, sum order (dx2+dy2)+dz2
      float dx = __fsub_rn(px[k], cx);
      float dy = __fsub_rn(py[k], cy);
      float dz = __fsub_rn(pz[k], cz);
      float d = __fadd_rn(__fadd_rn(__fmul_rn(dx, dx), __fmul_rn(dy, dy)), __fmul_rn(dz, dz));
      float mn = fminf(md[k], d);
      md[k] = mn;
      bool gt = mn > bestv;            // strict > keeps earliest k (= smallest j in-thread)
      bestv = gt ? mn : bestv;
      bestk = gt ? k : bestk;
    }
    int bestj = (sub << 11) + (bestk << 9) + tid;
    // wave reduce: DPP max ladder, then min-index among tied lanes (round-5 proven)
    float r = bestv;
    DPP_MAXF(r, 0x111); DPP_MAXF(r, 0x112); DPP_MAXF(r, 0x114);
    DPP_MAXF(r, 0x118); DPP_MAXF(r, 0x142); DPP_MAXF(r, 0x143);
    float wmax = __uint_as_float((unsigned)__builtin_amdgcn_readlane((int)__float_as_uint(r), 63));
    unsigned cj = (bestv == wmax) ? (unsigned)bestj : 0x7FFFFFFFu;
    DPP_MINU(cj, 0x111); DPP_MINU(cj, 0x112); DPP_MINU(cj, 0x114);
    DPP_MINU(cj, 0x118); DPP_MINU(cj, 0x142); DPP_MINU(cj, 0x143);
    unsigned jw = (unsigned)__builtin_amdgcn_readlane((int)cj, 63);
    if (lane == 0)
      part[wv] = ((unsigned long long)__float_as_uint(wmax) << 32) | (unsigned)(~jw);
    __syncthreads();
    if (tid == 0) {  // block winner -> tagged global slot
      unsigned long long g = part[0];
#pragma unroll
      for (int w = 1; w < 8; ++w) {
        unsigned long long o = part[w];
        g = (o > g) ? o : g;
      }
      unsigned jblk = ~(unsigned)g;                  // global j of block winner
      unsigned long long key = (g & 0xFFFFFFFF00000000ull) |
                               ((unsigned long long)(unsigned)(it & 1023) << 14) |
                               (16383u - jblk);
      __hip_atomic_store(&slots[p * NSUB + sub], key, __ATOMIC_RELAXED,
                         __HIP_MEMORY_SCOPE_AGENT);
    }
    if (tid < NSUB) {  // poll the 8 batch slots until this iteration's tag appears
      unsigned long long k = 0;
      int spins = 0;
      do {
        k = __hip_atomic_load(&slots[p * NSUB + tid], __ATOMIC_RELAXED,
                              __HIP_MEMORY_SCOPE_AGENT);
        if ((((unsigned)(k >> 14)) & 1023u) == (unsigned)(it & 1023)) break;
      } while (++spins < (1 << 17));   // bounded: deterministic fail, never a hang
      sh[tid] = k;
    }
    __syncthreads();
    // all threads merge the 8 slot keys (tags equal -> compare dist, then 16383-j)
    unsigned long long g2 = sh[0];
#pragma unroll
    for (int w = 1; w < NSUB; ++w) {
      unsigned long long o = sh[w];
      g2 = (o > g2) ? o : g2;
    }
    int js = 16383 - (int)(g2 & 0x3FFFu);
    js = __builtin_amdgcn_readfirstlane(js);         // uniform -> scalar loads
    const float* pc = base + 3 * js;
    cx = pc[0]; cy = pc[1]; cz = pc[2];              // bit-identical to source coords
    if (sub == 0 && tid == 0) { float* o3 = onew + 3 * it; o3[0] = cx; o3[1] = cy; o3[2] = cz; }
  }
}

// ---------------- Feature transpose: (B,C,N) -> (B,N,C), 64x64 LDS tiles ----------------
extern "C" __global__ __launch_bounds__(256)
void tr_kernel(const float* __restrict__ feats, float* __restrict__ featsT) {
  const int tile = blockIdx.x & 255;    // NN/64 = 256 tiles
  const int b = blockIdx.x >> 8;
  const int j0 = tile * 64;
  __shared__ float t[64][65];           // +1 pad: conflict-free both phases
  const int lj = threadIdx.x & 63;      // lane = j (read) / cc (write)
  const int r0 = threadIdx.x >> 6;      // 0..3
  const float* fb = feats + (size_t)b * (CIN * NN);
#pragma unroll
  for (int cc = r0; cc < 64; cc += 4)
    t[cc][lj] = fb[(size_t)cc * NN + j0 + lj];        // coalesced along j
  __syncthreads();
  float* ob = featsT + (size_t)b * (NN * CIN);
#pragma unroll
  for (int jr = r0; jr < 64; jr += 4)
    ob[(size_t)(j0 + jr) * 64 + lj] = t[lj][jr];      // coalesced along cc
}

// ---------------- Ball query: one wave per centroid, ordered append with early exit ----------------
extern "C" __global__ __launch_bounds__(256)
void ball_kernel(const float* __restrict__ xyz, const float* __restrict__ newxyz,
                 int* __restrict__ ballidx) {
  const int lwv = threadIdx.x >> 6, lane = threadIdx.x & 63;
  const int wid = blockIdx.x * 4 + lwv;  // centroid id, 0..4095
  const int b = wid >> 10;
  const float* base = xyz + (size_t)b * (NN * 3);
  const float* c = newxyz + (size_t)wid * 3;
  float cx = c[0], cy = c[1], cz = c[2];
  float c2 = __fadd_rn(__fadd_rn(__fmul_rn(cx, cx), __fmul_rn(cy, cy)), __fmul_rn(cz, cz));
  __shared__ int list[4][NS];
  int cnt = 0;
  for (int j0 = 0; j0 < NN; j0 += 64) {
    int j = j0 + lane;
    float xx = base[3 * j + 0], xy = base[3 * j + 1], xz = base[3 * j + 2];
    float x2 = __fadd_rn(__fadd_rn(__fmul_rn(xx, xx), __fmul_rn(xy, xy)), __fmul_rn(xz, xz));
    float dt = __fadd_rn(__fadd_rn(__fmul_rn(cx, xx), __fmul_rn(cy, xy)), __fmul_rn(cz, xz));
    float d2 = __fsub_rn(__fadd_rn(c2, x2), __fmul_rn(2.0f, dt));  // (c2+x2) - 2*dot
    bool in = d2 < 0.25f;
    unsigned long long msk = __ballot(in);
    if (in) {
      int pos = cnt + (int)__popcll(msk & ((1ull << lane) - 1ull));
      if (pos < NS) list[lwv][pos] = j;
    }
    cnt += (int)__popcll(msk);
    if (cnt >= NS) break;
  }
  if (lane < NS) {
    int v;
    if (cnt == 0) v = 0;
    else v = (lane < cnt) ? list[lwv][lane] : list[lwv][0];
    ballidx[wid * NS + lane] = v;
  }
}

// ---------------- Gather + MLP(67->64->64->128) + max-pool, one block per (b,m) ----------------
extern "C" __global__ __launch_bounds__(256)
void mlp_kernel(const float* __restrict__ xyz, const float* __restrict__ feats,
                const float* __restrict__ featsT,   // point-major copy, or null (fallback)
                const float* __restrict__ newxyz, const int* __restrict__ ballidx,
                const float* __restrict__ W1, const float* __restrict__ b1,
                const float* __restrict__ W2, const float* __restrict__ b2,
                const float* __restrict__ W3, const float* __restrict__ b3,
                float* __restrict__ outf) {
  const int bm = blockIdx.x;
  const int b = bm >> 10, m = bm & 1023;
  const int tid = threadIdx.x;
  __align__(16) __shared__ float bufA[32 * 68];  // h0 (stride 68), then h2 (stride 64)
  __align__(16) __shared__ float bufB[32 * 64];  // h1, then partial max
  __shared__ int sidx[NS];
  if (tid < NS) sidx[tid] = ballidx[bm * NS + tid];
  const float* cb = newxyz + (size_t)bm * 3;
  float cx = cb[0], cy = cb[1], cz = cb[2];
  __syncthreads();
  // gather: 8 threads per sample
  {
    int s = tid >> 3, q = tid & 7;
    int j = sidx[s];
    float* row = bufA + s * 68;
    if (featsT) {
      const float* fr = featsT + ((size_t)b * NN + j) * 64 + (q << 3);
      float4 a0 = *(const float4*)fr;
      float4 a1 = *(const float4*)(fr + 4);
      float* rp = row + 3 + (q << 3);
      rp[0] = a0.x; rp[1] = a0.y; rp[2] = a0.z; rp[3] = a0.w;
      rp[4] = a1.x; rp[5] = a1.y; rp[6] = a1.z; rp[7] = a1.w;
    } else {
      const float* fb = feats + (size_t)b * (CIN * NN) + j;
#pragma unroll
      for (int u = 0; u < 8; ++u) {
        int cc = (q << 3) + u;
        row[3 + cc] = fb[(size_t)cc * NN];
      }
    }
    if (q == 0) {
      const float* p = xyz + ((size_t)b * NN + j) * 3;
      row[0] = __fsub_rn(p[0], cx);
      row[1] = __fsub_rn(p[1], cy);
      row[2] = __fsub_rn(p[2], cz);
      row[67] = 0.0f;
    }
  }
  __syncthreads();
  // layer 1: 67->64   (thread = (o, 8-sample group))
  {
    const int o = tid & 63, g = tid >> 6;
    float w[68];
    const float* wr = W1 + o * C0;
#pragma unroll
    for (int c = 0; c < C0; ++c) w[c] = wr[c];
    w[67] = 0.0f;
    float bias = b1[o];
    float acc[8];
#pragma unroll
    for (int k = 0; k < 8; ++k) acc[k] = bias;
#pragma unroll
    for (int c = 0; c < 68; c += 4) {
#pragma unroll
      for (int k = 0; k < 8; ++k) {
        float4 h = *(const float4*)(bufA + (g * 8 + k) * 68 + c);
        acc[k] = fmaf(w[c], h.x, acc[k]);
        acc[k] = fmaf(w[c + 1], h.y, acc[k]);
        acc[k] = fmaf(w[c + 2], h.z, acc[k]);
        acc[k] = fmaf(w[c + 3], h.w, acc[k]);
      }
    }
#pragma unroll
    for (int k = 0; k < 8; ++k) bufB[(g * 8 + k) * 64 + o] = fmaxf(acc[k], 0.0f);
  }
  __syncthreads();
  // layer 2: 64->64, h2 into bufA with stride 64
  {
    const int o = tid & 63, g = tid >> 6;
    float w[64];
    const float* wr = W2 + o * 64;
#pragma unroll
    for (int c = 0; c < 64; ++c) w[c] = wr[c];
    float bias = b2[o];
    float acc[8];
#pragma unroll
    for (int k = 0; k < 8; ++k) acc[k] = bias;
#pragma unroll
    for (int c = 0; c < 64; c += 4) {
#pragma unroll
      for (int k = 0; k < 8; ++k) {
        float4 h = *(const float4*)(bufB + (g * 8 + k) * 64 + c);
        acc[k] = fmaf(w[c], h.x, acc[k]);
        acc[k] = fmaf(w[c + 1], h.y, acc[k]);
        acc[k] = fmaf(w[c + 2], h.z, acc[k]);
        acc[k] = fmaf(w[c + 3], h.w, acc[k]);
      }
    }
#pragma unroll
    for (int k = 0; k < 8; ++k) bufA[(g * 8 + k) * 64 + o] = fmaxf(acc[k], 0.0f);
  }
  __syncthreads();
  // layer 3: 64->128 (thread = (o128, 16-sample group)), fused relu+max
  {
    const int o = tid & 127, g = tid >> 7;
    float w[64];
    const float* wr = W3 + o * 64;
#pragma unroll
    for (int c = 0; c < 64; ++c) w[c] = wr[c];
    float bias = b3[o];
    float acc[16];
#pragma unroll
    for (int k = 0; k < 16; ++k) acc[k] = bias;
#pragma unroll
    for (int kb = 0; kb < 16; kb += 8) {   // 8-sample sub-blocks to limit live registers
#pragma unroll
      for (int c = 0; c < 64; c += 4) {
#pragma unroll
        for (int k = 0; k < 8; ++k) {
          float4 h = *(const float4*)(bufA + (g * 16 + kb + k) * 64 + c);
          acc[kb + k] = fmaf(w[c], h.x, acc[kb + k]);
          acc[kb + k] = fmaf(w[c + 1], h.y, acc[kb + k]);
          acc[kb + k] = fmaf(w[c + 2], h.z, acc[kb + k]);
          acc[kb + k] = fmaf(w[c + 3], h.w, acc[kb + k]);
        }
      }
    }
    float mx = 0.0f;
#pragma unroll
    for (int k = 0; k < 16; ++k) mx = fmaxf(mx, fmaxf(acc[k], 0.0f));
    bufB[g * 128 + o] = mx;
  }
  __syncthreads();
  if (tid < 128) {
    float v = fmaxf(bufB[tid], bufB[128 + tid]);
    outf[((size_t)b * 128 + tid) * NPT + m] = v;
  }
}

extern "C" void kernel_launch(void* const* d_in, const int* in_sizes, int n_in,
                              void* d_out, int out_size, void* d_ws, size_t ws_size,
                              hipStream_t stream) {
  const float* xyz   = (const float*)d_in[0];
  const float* feats = (const float*)d_in[1];
  const float* W1 = (const float*)d_in[2];
  const float* b1 = (const float*)d_in[3];
  const float* W2 = (const float*)d_in[4];
  const float* b2 = (const float*)d_in[5];
  const float* W3 = (const float*)d_in[6];
  const float* b3 = (const float*)d_in[7];
  float* out = (float*)d_out;
  float* newxyz = out;                 // (4,1024,3)
  float* outf = out + NB * NPT * 3;    // (4,128,1024)
  int* ballidx = (int*)d_ws;           // 4096*32 ints at ws+0 (512 KB)

  // FPS winner slots: 4 batches x 2 parity x 8 subs x 8B = 512 B at ws+512K
  unsigned long long* win = (unsigned long long*)((char*)d_ws + (512u << 10));
  // featsT (16.78 MB) at ws+1MB if the workspace allows; else fall back to strided gather
  const size_t ftOff = 1u << 20;
  const size_t ftBytes = (size_t)NB * NN * CIN * sizeof(float);
  float* featsT = (ws_size >= ftOff + ftBytes) ? (float*)((char*)d_ws + ftOff) : nullptr;

  if (featsT)
    hipLaunchKernelGGL(tr_kernel, dim3(NB * (NN / 64)), dim3(256), 0, stream, feats, featsT);
  hipLaunchKernelGGL(fps_kernel, dim3(NB * NSUB), dim3(512), 0, stream, xyz, newxyz, win);
  hipLaunchKernelGGL(ball_kernel, dim3(NB * NPT / 4), dim3(256), 0, stream, xyz, newxyz, ballidx);
  hipLaunchKernelGGL(mlp_kernel, dim3(NB * NPT), dim3(256), 0, stream,
                     xyz, feats, featsT, newxyz, ballidx, W1, b1, W2, b2, W3, b3, outf);
}

// Round 9
// 1808.037 us; speedup vs baseline: 1.0599x; 1.0599x over previous
//
#include <hip/hip_runtime.h>

#define NB 4
#define NN 16384
#define NPT 1024
#define NS 32
#define CIN 64
#define C0 67

typedef float v2f __attribute__((ext_vector_type(2)));

// DPP wave64 reduce ladders (VALU-only; HW-verified correct in rounds 3/5/6 passing runs)
#define DPP_MAXF(r, ctrl)                                                                   \
  {                                                                                         \
    unsigned _m = (unsigned)__builtin_amdgcn_update_dpp(                                    \
        (int)__float_as_uint(r), (int)__float_as_uint(r), ctrl, 0xf, 0xf, false);           \
    r = fmaxf(r, __uint_as_float(_m));                                                      \
  }
#define DPP_MINU(r, ctrl)                                                                   \
  {                                                                                         \
    unsigned _m = (unsigned)__builtin_amdgcn_update_dpp((int)(r), (int)(r), ctrl, 0xf, 0xf, \
                                                        false);                             \
    r = (r < _m) ? r : _m;                                                                  \
  }

// ---------------- FPS: one block per batch, 512 threads, 32 pts/thread ----------------
// RESTORED round-6 proven kernel (1546us). Structure-space verdict across 7 probes:
// 1024thr=1837, 512thr=1546 (best), LDS-staged=1841, asm-pinned=fail, pk+DPP=1546,
// 8x512 multiblock=1659 (cross-XCD exchange ~3500cyc/iter > whole single-block iter),
// 8x64 multiblock=container fail. FPS is a strictly serial 1023-iteration argmax chain;
// 1546us is the empirical floor of every reachable structure. Do not churn.
extern "C" __global__ __attribute__((amdgpu_waves_per_eu(2, 2))) __launch_bounds__(512)
void fps_kernel(const float* __restrict__ xyz, float* __restrict__ newxyz) {
  const int b = blockIdx.x;
  const int tid = threadIdx.x;          // 0..511
  const int wv = tid >> 6, lane = tid & 63;
  const float* base = xyz + (size_t)b * (NN * 3);
  __shared__ unsigned long long part[2][8];  // parity-double-buffered wave-winner keys
  v2f x2[16], y2[16], z2[16], m2[16];
#pragma unroll
  for (int k = 0; k < 32; ++k) {
    int j = (k << 9) + tid;            // same global index mapping as rounds 0-6
    x2[k >> 1][k & 1] = base[3 * j + 0];
    y2[k >> 1][k & 1] = base[3 * j + 1];
    z2[k >> 1][k & 1] = base[3 * j + 2];
    m2[k >> 1][k & 1] = 1e10f;
  }
  float* onew = newxyz + (size_t)b * (NPT * 3);
  // iteration 0: centroid = point 0 (broadcast load)
  float cx = base[0], cy = base[1], cz = base[2];
  if (tid == 0) { onew[0] = cx; onew[1] = cy; onew[2] = cz; }
  v2f cx2 = {cx, cx}, cy2 = {cy, cy}, cz2 = {cz, cz};
  for (int it = 1; it < NPT; ++it) {
    const int p = it & 1;
    float bv = -1.0f;
    {
#pragma clang fp contract(off)
#pragma unroll
      for (int q = 0; q < 16; ++q) {
        v2f dx = x2[q] - cx2;          // exact IEEE sub per half
        v2f dy = y2[q] - cy2;
        v2f dz = z2[q] - cz2;
        v2f qx = dx * dx;              // no contraction (pragma)
        v2f qy = dy * dy;
        v2f qz = dz * dz;
        v2f ss = qx + qy;              // (dx2+dy2)
        v2f dd = ss + qz;              // +dz2   -- reference's exact order
        float a = fminf(m2[q].x, dd.x);
        float bmn = fminf(m2[q].y, dd.y);
        m2[q].x = a;
        m2[q].y = bmn;
        bv = fmaxf(bv, fmaxf(a, bmn)); // fuses to v_max3_f32
      }
    }
    // post-scan: smallest k with md[k]==bv (descending overwrite keeps smallest)
    int bk = 0;
#pragma unroll
    for (int k = 31; k >= 0; --k) {
      float v = (k & 1) ? m2[k >> 1].y : m2[k >> 1].x;
      bk = (v == bv) ? k : bk;
    }
    int bestj = (bk << 9) + tid;
    // phase A: wave max of bv via DPP ladder -> lane 63
    float r = bv;
    DPP_MAXF(r, 0x111); DPP_MAXF(r, 0x112); DPP_MAXF(r, 0x114);
    DPP_MAXF(r, 0x118); DPP_MAXF(r, 0x142); DPP_MAXF(r, 0x143);
    float wmax = __uint_as_float((unsigned)__builtin_amdgcn_readlane((int)__float_as_uint(r), 63));
    // phase B: min index among lanes holding the max (exact equality: min/max return operands)
    unsigned cj = (bv == wmax) ? (unsigned)bestj : 0x7FFFFFFFu;
    DPP_MINU(cj, 0x111); DPP_MINU(cj, 0x112); DPP_MINU(cj, 0x114);
    DPP_MINU(cj, 0x118); DPP_MINU(cj, 0x142); DPP_MINU(cj, 0x143);
    unsigned jw = (unsigned)__builtin_amdgcn_readlane((int)cj, 63);
    if (lane == 0)
      part[p][wv] = ((unsigned long long)__float_as_uint(wmax) << 32) | (unsigned)(~jw);
    __syncthreads();
    // every thread merges the 8 wave winners (broadcast LDS reads); ~j orders ties to min j
    unsigned long long g = part[p][0];
#pragma unroll
    for (int w = 1; w < 8; ++w) {
      unsigned long long o = part[p][w];
      g = (o > g) ? o : g;
    }
    int j = (int)(~(unsigned)g);
    int js = __builtin_amdgcn_readfirstlane(j);      // uniform -> scalar loads
    const float* pc = base + 3 * js;
    cx = pc[0]; cy = pc[1]; cz = pc[2];              // bit-identical to source coords
    if (tid == 0) { float* o3 = onew + 3 * it; o3[0] = cx; o3[1] = cy; o3[2] = cz; }
    cx2.x = cx; cx2.y = cx;
    cy2.x = cy; cy2.y = cy;
    cz2.x = cz; cz2.y = cz;
    // no second barrier: next iteration writes the OTHER parity's part[] cells
  }
}

// ---------------- Feature transpose: (B,C,N) -> (B,N,C), 64x64 LDS tiles ----------------
// mlp's gather reads feats[cc*NN + j] at scattered j: 64 lanes x 64 distinct 64B lines,
// 4B used each => ~16x line-waste on the L2/L3 path. One 16.8MB point-major copy makes
// each sample's 64 channels one contiguous 256B read. Bit-preserving (pure copy).
extern "C" __global__ __launch_bounds__(256)
void tr_kernel(const float* __restrict__ feats, float* __restrict__ featsT) {
  const int tile = blockIdx.x & 255;    // NN/64 = 256 tiles
  const int b = blockIdx.x >> 8;
  const int j0 = tile * 64;
  __shared__ float t[64][65];           // +1 pad: conflict-free both phases
  const int lj = threadIdx.x & 63;      // lane = j (read) / cc (write)
  const int r0 = threadIdx.x >> 6;      // 0..3
  const float* fb = feats + (size_t)b * (CIN * NN);
#pragma unroll
  for (int cc = r0; cc < 64; cc += 4)
    t[cc][lj] = fb[(size_t)cc * NN + j0 + lj];        // coalesced along j
  __syncthreads();
  float* ob = featsT + (size_t)b * (NN * CIN);
#pragma unroll
  for (int jr = r0; jr < 64; jr += 4)
    ob[(size_t)(j0 + jr) * 64 + lj] = t[lj][jr];      // coalesced along cc
}

// ---------------- Ball query: one wave per centroid, ordered append with early exit ----------------
extern "C" __global__ __launch_bounds__(256)
void ball_kernel(const float* __restrict__ xyz, const float* __restrict__ newxyz,
                 int* __restrict__ ballidx) {
  const int lwv = threadIdx.x >> 6, lane = threadIdx.x & 63;
  const int wid = blockIdx.x * 4 + lwv;  // centroid id, 0..4095
  const int b = wid >> 10;
  const float* base = xyz + (size_t)b * (NN * 3);
  const float* c = newxyz + (size_t)wid * 3;
  float cx = c[0], cy = c[1], cz = c[2];
  float c2 = __fadd_rn(__fadd_rn(__fmul_rn(cx, cx), __fmul_rn(cy, cy)), __fmul_rn(cz, cz));
  __shared__ int list[4][NS];
  int cnt = 0;
  for (int j0 = 0; j0 < NN; j0 += 64) {
    int j = j0 + lane;
    float xx = base[3 * j + 0], xy = base[3 * j + 1], xz = base[3 * j + 2];
    float x2 = __fadd_rn(__fadd_rn(__fmul_rn(xx, xx), __fmul_rn(xy, xy)), __fmul_rn(xz, xz));
    float dt = __fadd_rn(__fadd_rn(__fmul_rn(cx, xx), __fmul_rn(cy, xy)), __fmul_rn(cz, xz));
    float d2 = __fsub_rn(__fadd_rn(c2, x2), __fmul_rn(2.0f, dt));  // (c2+x2) - 2*dot
    bool in = d2 < 0.25f;
    unsigned long long msk = __ballot(in);
    if (in) {
      int pos = cnt + (int)__popcll(msk & ((1ull << lane) - 1ull));
      if (pos < NS) list[lwv][pos] = j;
    }
    cnt += (int)__popcll(msk);
    if (cnt >= NS) break;
  }
  if (lane < NS) {
    int v;
    if (cnt == 0) v = 0;
    else v = (lane < cnt) ? list[lwv][lane] : list[lwv][0];
    ballidx[wid * NS + lane] = v;
  }
}

// ---------------- Gather + MLP(67->64->64->128) + max-pool, one block per (b,m) ----------------
extern "C" __global__ __launch_bounds__(256)
void mlp_kernel(const float* __restrict__ xyz, const float* __restrict__ feats,
                const float* __restrict__ featsT,   // point-major copy, or null (fallback)
                const float* __restrict__ newxyz, const int* __restrict__ ballidx,
                const float* __restrict__ W1, const float* __restrict__ b1,
                const float* __restrict__ W2, const float* __restrict__ b2,
                const float* __restrict__ W3, const float* __restrict__ b3,
                float* __restrict__ outf) {
  const int bm = blockIdx.x;
  const int b = bm >> 10, m = bm & 1023;
  const int tid = threadIdx.x;
  __align__(16) __shared__ float bufA[32 * 68];  // h0 (stride 68), then h2 (stride 64)
  __align__(16) __shared__ float bufB[32 * 64];  // h1, then partial max
  __shared__ int sidx[NS];
  if (tid < NS) sidx[tid] = ballidx[bm * NS + tid];
  const float* cb = newxyz + (size_t)bm * 3;
  float cx = cb[0], cy = cb[1], cz = cb[2];
  __syncthreads();
  // gather: 8 threads per sample
  {
    int s = tid >> 3, q = tid & 7;
    int j = sidx[s];
    float* row = bufA + s * 68;
    if (featsT) {
      const float* fr = featsT + ((size_t)b * NN + j) * 64 + (q << 3);
      float4 a0 = *(const float4*)fr;
      float4 a1 = *(const float4*)(fr + 4);
      float* rp = row + 3 + (q << 3);
      rp[0] = a0.x; rp[1] = a0.y; rp[2] = a0.z; rp[3] = a0.w;
      rp[4] = a1.x; rp[5] = a1.y; rp[6] = a1.z; rp[7] = a1.w;
    } else {
      const float* fb = feats + (size_t)b * (CIN * NN) + j;
#pragma unroll
      for (int u = 0; u < 8; ++u) {
        int cc = (q << 3) + u;
        row[3 + cc] = fb[(size_t)cc * NN];
      }
    }
    if (q == 0) {
      const float* p = xyz + ((size_t)b * NN + j) * 3;
      row[0] = __fsub_rn(p[0], cx);
      row[1] = __fsub_rn(p[1], cy);
      row[2] = __fsub_rn(p[2], cz);
      row[67] = 0.0f;
    }
  }
  __syncthreads();
  // layer 1: 67->64   (thread = (o, 8-sample group))
  {
    const int o = tid & 63, g = tid >> 6;
    float w[68];
    const float* wr = W1 + o * C0;
#pragma unroll
    for (int c = 0; c < C0; ++c) w[c] = wr[c];
    w[67] = 0.0f;
    float bias = b1[o];
    float acc[8];
#pragma unroll
    for (int k = 0; k < 8; ++k) acc[k] = bias;
#pragma unroll
    for (int c = 0; c < 68; c += 4) {
#pragma unroll
      for (int k = 0; k < 8; ++k) {
        float4 h = *(const float4*)(bufA + (g * 8 + k) * 68 + c);
        acc[k] = fmaf(w[c], h.x, acc[k]);
        acc[k] = fmaf(w[c + 1], h.y, acc[k]);
        acc[k] = fmaf(w[c + 2], h.z, acc[k]);
        acc[k] = fmaf(w[c + 3], h.w, acc[k]);
      }
    }
#pragma unroll
    for (int k = 0; k < 8; ++k) bufB[(g * 8 + k) * 64 + o] = fmaxf(acc[k], 0.0f);
  }
  __syncthreads();
  // layer 2: 64->64, h2 into bufA with stride 64
  {
    const int o = tid & 63, g = tid >> 6;
    float w[64];
    const float* wr = W2 + o * 64;
#pragma unroll
    for (int c = 0; c < 64; ++c) w[c] = wr[c];
    float bias = b2[o];
    float acc[8];
#pragma unroll
    for (int k = 0; k < 8; ++k) acc[k] = bias;
#pragma unroll
    for (int c = 0; c < 64; c += 4) {
#pragma unroll
      for (int k = 0; k < 8; ++k) {
        float4 h = *(const float4*)(bufB + (g * 8 + k) * 64 + c);
        acc[k] = fmaf(w[c], h.x, acc[k]);
        acc[k] = fmaf(w[c + 1], h.y, acc[k]);
        acc[k] = fmaf(w[c + 2], h.z, acc[k]);
        acc[k] = fmaf(w[c + 3], h.w, acc[k]);
      }
    }
#pragma unroll
    for (int k = 0; k < 8; ++k) bufA[(g * 8 + k) * 64 + o] = fmaxf(acc[k], 0.0f);
  }
  __syncthreads();
  // layer 3: 64->128 (thread = (o128, 16-sample group)), fused relu+max
  {
    const int o = tid & 127, g = tid >> 7;
    float w[64];
    const float* wr = W3 + o * 64;
#pragma unroll
    for (int c = 0; c < 64; ++c) w[c] = wr[c];
    float bias = b3[o];
    float acc[16];
#pragma unroll
    for (int k = 0; k < 16; ++k) acc[k] = bias;
#pragma unroll
    for (int kb = 0; kb < 16; kb += 8) {   // 8-sample sub-blocks to limit live registers
#pragma unroll
      for (int c = 0; c < 64; c += 4) {
#pragma unroll
        for (int k = 0; k < 8; ++k) {
          float4 h = *(const float4*)(bufA + (g * 16 + kb + k) * 64 + c);
          acc[kb + k] = fmaf(w[c], h.x, acc[kb + k]);
          acc[kb + k] = fmaf(w[c + 1], h.y, acc[kb + k]);
          acc[kb + k] = fmaf(w[c + 2], h.z, acc[kb + k]);
          acc[kb + k] = fmaf(w[c + 3], h.w, acc[kb + k]);
        }
      }
    }
    float mx = 0.0f;
#pragma unroll
    for (int k = 0; k < 16; ++k) mx = fmaxf(mx, fmaxf(acc[k], 0.0f));
    bufB[g * 128 + o] = mx;
  }
  __syncthreads();
  if (tid < 128) {
    float v = fmaxf(bufB[tid], bufB[128 + tid]);
    outf[((size_t)b * 128 + tid) * NPT + m] = v;
  }
}

extern "C" void kernel_launch(void* const* d_in, const int* in_sizes, int n_in,
                              void* d_out, int out_size, void* d_ws, size_t ws_size,
                              hipStream_t stream) {
  const float* xyz   = (const float*)d_in[0];
  const float* feats = (const float*)d_in[1];
  const float* W1 = (const float*)d_in[2];
  const float* b1 = (const float*)d_in[3];
  const float* W2 = (const float*)d_in[4];
  const float* b2 = (const float*)d_in[5];
  const float* W3 = (const float*)d_in[6];
  const float* b3 = (const float*)d_in[7];
  float* out = (float*)d_out;
  float* newxyz = out;                 // (4,1024,3)
  float* outf = out + NB * NPT * 3;    // (4,128,1024)
  int* ballidx = (int*)d_ws;           // 4096*32 ints at ws+0

  // featsT (16.78 MB) lives at ws+1MB if the workspace is big enough; else fall back
  const size_t ftOff = 1u << 20;
  const size_t ftBytes = (size_t)NB * NN * CIN * sizeof(float);
  float* featsT = (ws_size >= ftOff + ftBytes) ? (float*)((char*)d_ws + ftOff) : nullptr;

  if (featsT)
    hipLaunchKernelGGL(tr_kernel, dim3(NB * (NN / 64)), dim3(256), 0, stream, feats, featsT);
  hipLaunchKernelGGL(fps_kernel, dim3(NB), dim3(512), 0, stream, xyz, newxyz);
  hipLaunchKernelGGL(ball_kernel, dim3(NB * NPT / 4), dim3(256), 0, stream, xyz, newxyz, ballidx);
  hipLaunchKernelGGL(mlp_kernel, dim3(NB * NPT), dim3(256), 0, stream,
                     xyz, feats, featsT, newxyz, ballidx, W1, b1, W2, b2, W3, b3, outf);
}